// Round 1
// baseline (41.754 us; speedup 1.0000x reference)
//
#include <hip/hip_runtime.h>
#include <math.h>

#define T 16
#define A 8
#define H 128
#define E 32
#define G (4*H)   // 512 gate rows per LSTM

__device__ __forceinline__ float sigmoidf_(float x) {
    // safe at extremes: x<<0 -> exp(-x)=inf -> 0 ; x>>0 -> 1
    return 1.0f / (1.0f + __expf(-x));
}
__device__ __forceinline__ float tanhf_(float x) {
    // tanh(x) = 1 - 2/(1+e^{2x}); safe at both extremes (no inf/inf)
    return 1.0f - 2.0f / (1.0f + __expf(2.0f * x));
}

__global__ __launch_bounds__(512, 2)
void ppo_ctrl_kernel(const int* __restrict__ old_actions,
                     const float* __restrict__ init_input,
                     const float* __restrict__ W_ih_a, const float* __restrict__ W_hh_a,
                     const float* __restrict__ b_ih_a, const float* __restrict__ b_hh_a,
                     const float* __restrict__ heads_W, const float* __restrict__ heads_b,
                     const float* __restrict__ W_ih_c, const float* __restrict__ W_hh_c,
                     const float* __restrict__ b_ih_c, const float* __restrict__ b_hh_c,
                     const float* __restrict__ critic_W, const float* __restrict__ critic_b,
                     const float* __restrict__ embed,
                     float* __restrict__ out)
{
    const int tid  = threadIdx.x;
    const int lane = tid & 63;
    const int wv   = tid >> 6;          // 8 waves
    const bool actor = (blockIdx.x == 0);

    const float* W_ih = actor ? W_ih_a : W_ih_c;
    const float* W_hh = actor ? W_hh_a : W_hh_c;
    const float* b_ih = actor ? b_ih_a : b_ih_c;
    const float* b_hh = actor ? b_hh_a : b_hh_c;

    __shared__ __align__(16) float x_s[T][E];   // 2 KB input sequence
    __shared__ __align__(16) float h_s[H];      // current hidden
    __shared__ float gates_s[G];                // 2 KB gate scratch
    __shared__ float logit_s[A];

    // ---- build x sequence (512 elements == 512 threads, one each) ----
    {
        int t = tid / E, e = tid % E;   // T*E == 512 exactly
        float v;
        if (t == 0) v = init_input[e];
        else        v = embed[((t - 1) * A + old_actions[t - 1]) * E + e];
        x_s[t][e] = v;
    }
    if (tid < H) h_s[tid] = 0.0f;

    // ---- weights into registers (one gate row per thread) ----
    float w_ih[E];
    float w_hh[H];
    #pragma unroll
    for (int e = 0; e < E; e += 4) {
        float4 v = *(const float4*)(W_ih + tid * E + e);
        w_ih[e+0] = v.x; w_ih[e+1] = v.y; w_ih[e+2] = v.z; w_ih[e+3] = v.w;
    }
    #pragma unroll
    for (int k = 0; k < H; k += 4) {
        float4 v = *(const float4*)(W_hh + tid * H + k);
        w_hh[k+0] = v.x; w_hh[k+1] = v.y; w_hh[k+2] = v.z; w_hh[k+3] = v.w;
    }
    const float bias = b_ih[tid] + b_hh[tid];

    // critic head weights (t-invariant), wave 0 of critic block
    float cw0 = 0.f, cw1 = 0.f, cb = 0.f;
    if (!actor && wv == 0) {
        cw0 = critic_W[lane];
        cw1 = critic_W[64 + lane];
        cb  = critic_b[0];
    }

    float c_reg = 0.0f;   // cell state, threads 0..127

    __syncthreads();

    for (int t = 0; t < T; ++t) {
        // prefetch this step's actor head weights (independent of h)
        float hw0 = 0.f, hw1 = 0.f, hb = 0.f;
        if (actor) {
            const float* hw = heads_W + (t * A + wv) * H;
            hw0 = hw[lane];
            hw1 = hw[64 + lane];
            hb  = heads_b[t * A + wv];
        }

        // ---- gate matvec: 160 register-FMAs, h/x broadcast from LDS ----
        float acc = bias;
        #pragma unroll
        for (int e = 0; e < E; e += 4) {
            float4 xv = *(const float4*)(&x_s[t][e]);
            acc += w_ih[e+0]*xv.x + w_ih[e+1]*xv.y + w_ih[e+2]*xv.z + w_ih[e+3]*xv.w;
        }
        #pragma unroll
        for (int k = 0; k < H; k += 4) {
            float4 hv = *(const float4*)(&h_s[k]);
            acc += w_hh[k+0]*hv.x + w_hh[k+1]*hv.y + w_hh[k+2]*hv.z + w_hh[k+3]*hv.w;
        }
        gates_s[tid] = acc;
        __syncthreads();

        // ---- cell/hidden update (PyTorch gate order i,f,g,o) ----
        if (tid < H) {
            float gi = gates_s[tid];
            float gf = gates_s[tid + H];
            float gg = gates_s[tid + 2*H];
            float go = gates_s[tid + 3*H];
            float cn = sigmoidf_(gf) * c_reg + sigmoidf_(gi) * tanhf_(gg);
            c_reg = cn;
            h_s[tid] = sigmoidf_(go) * tanhf_(cn);
        }
        __syncthreads();

        // ---- heads ----
        if (actor) {
            // wave wv computes logit wv
            float p = hw0 * h_s[lane] + hw1 * h_s[64 + lane];
            #pragma unroll
            for (int off = 32; off > 0; off >>= 1) p += __shfl_down(p, off);
            if (lane == 0) logit_s[wv] = p + hb;
        } else if (wv == 0) {
            float p = cw0 * h_s[lane] + cw1 * h_s[64 + lane];
            #pragma unroll
            for (int off = 32; off > 0; off >>= 1) p += __shfl_down(p, off);
            if (lane == 0) out[2 * T + t] = p + cb;   // values
        }
        __syncthreads();

        if (actor && tid == 0) {
            float m = logit_s[0];
            #pragma unroll
            for (int a = 1; a < A; ++a) m = fmaxf(m, logit_s[a]);
            float s = 0.f;
            #pragma unroll
            for (int a = 0; a < A; ++a) s += __expf(logit_s[a] - m);
            float logZ = m + __logf(s);
            int act = old_actions[t];
            out[t] = logit_s[act] - logZ;             // log_probs
            float ent = 0.f;
            #pragma unroll
            for (int a = 0; a < A; ++a) {
                float lp = logit_s[a] - logZ;
                ent -= __expf(lp) * lp;
            }
            out[T + t] = ent;                         // entropies
        }
    }
}

extern "C" void kernel_launch(void* const* d_in, const int* in_sizes, int n_in,
                              void* d_out, int out_size, void* d_ws, size_t ws_size,
                              hipStream_t stream) {
    const int*   old_actions = (const int*)  d_in[0];
    const float* init_input  = (const float*)d_in[1];
    const float* W_ih_a      = (const float*)d_in[2];
    const float* W_hh_a      = (const float*)d_in[3];
    const float* b_ih_a      = (const float*)d_in[4];
    const float* b_hh_a      = (const float*)d_in[5];
    const float* heads_W     = (const float*)d_in[6];
    const float* heads_b     = (const float*)d_in[7];
    const float* W_ih_c      = (const float*)d_in[8];
    const float* W_hh_c      = (const float*)d_in[9];
    const float* b_ih_c      = (const float*)d_in[10];
    const float* b_hh_c      = (const float*)d_in[11];
    const float* critic_W    = (const float*)d_in[12];
    const float* critic_b    = (const float*)d_in[13];
    const float* embed       = (const float*)d_in[14];
    float* out = (float*)d_out;

    ppo_ctrl_kernel<<<dim3(2), dim3(512), 0, stream>>>(
        old_actions, init_input,
        W_ih_a, W_hh_a, b_ih_a, b_hh_a,
        heads_W, heads_b,
        W_ih_c, W_hh_c, b_ih_c, b_hh_c,
        critic_W, critic_b, embed, out);
}